// Round 1
// baseline (732.741 us; speedup 1.0000x reference)
//
#include <hip/hip_runtime.h>
#include <math.h>

// Problem constants (from reference): B,H,U,C,K = 256,1024,1024,512,10
#define BB 256
#define HH 1024
#define UU 1024
#define CC 512
#define KK 10
#define UCHUNK 128   // u-rows per window block

__device__ __forceinline__ float softplus_f(float x) {
    // numerically stable: max(x,0) + log1p(exp(-|x|))
    return fmaxf(x, 0.0f) + log1pf(expf(-fabsf(x)));
}

// One block per batch row b. 256 threads = 4 waves.
// Computes params[30] = h[b] @ W.T + bias, then alpha/beta/kappa.
__global__ void softwindow_params(const float* __restrict__ h,
                                  const float* __restrict__ k_prev,
                                  const float* __restrict__ W,
                                  const float* __restrict__ bias,
                                  float* __restrict__ alpha,
                                  float* __restrict__ beta,
                                  float* __restrict__ kappa_ws,
                                  float* __restrict__ kappa_out) {
    __shared__ float sh[HH];
    __shared__ float sparams[3 * KK];
    const int b = blockIdx.x;
    const int t = threadIdx.x;            // 0..255

    // stage h row: 1024 floats = 256 float4
    ((float4*)sh)[t] = ((const float4*)(h + (size_t)b * HH))[t];
    __syncthreads();

    const int wave = t >> 6;
    const int lane = t & 63;
    for (int j = wave; j < 3 * KK; j += 4) {
        const float* wrow = W + (size_t)j * HH;
        float sum = 0.0f;
        #pragma unroll
        for (int l = lane; l < HH; l += 64) sum += sh[l] * wrow[l];
        // wave64 shuffle reduction
        #pragma unroll
        for (int off = 32; off > 0; off >>= 1) sum += __shfl_down(sum, off);
        if (lane == 0) sparams[j] = sum + bias[j];
    }
    __syncthreads();

    if (t < KK) {
        float a  = softplus_f(sparams[t]) + 1e-4f;
        float be = fminf(fmaxf(softplus_f(sparams[KK + t]), 0.1f), 10.0f);
        float ka = k_prev[b * KK + t] + softplus_f(sparams[2 * KK + t]) * 0.1f;
        alpha[b * KK + t]    = a;
        beta[b * KK + t]     = be;
        kappa_ws[b * KK + t] = ka;
        kappa_out[b * KK + t] = ka;   // third output
    }
}

// Fused phi + window. Grid: (UU/UCHUNK, BB), block = UCHUNK = 128 threads.
// Each thread: phi for one u; then all threads stream the c_seq tile
// (UCHUNK x CC) with float4 loads, 4 c-columns per thread.
__global__ void softwindow_window(const float* __restrict__ c_seq,
                                  const float* __restrict__ alpha,
                                  const float* __restrict__ beta,
                                  const float* __restrict__ kappa,
                                  float* __restrict__ window,
                                  float* __restrict__ phi_out) {
    __shared__ float sphi[UCHUNK];
    const int b  = blockIdx.y;
    const int u0 = blockIdx.x * UCHUNK;
    const int t  = threadIdx.x;           // 0..127

    // phi for u = u0 + t
    const float uf = (float)(u0 + t);
    float p = 0.0f;
    #pragma unroll
    for (int k = 0; k < KK; ++k) {
        const float a  = alpha[b * KK + k];
        const float be = beta[b * KK + k];
        const float ka = kappa[b * KK + k];
        const float d  = ka - uf;
        p += a * __expf(-be * d * d);     // underflows cleanly to 0 for large |d|
    }
    sphi[t] = p;
    phi_out[(size_t)b * UU + u0 + t] = p; // second output
    __syncthreads();

    // stream the tile: 128 u-rows x 512 c, float4 per thread per row
    const float4* tile = (const float4*)(c_seq + (size_t)b * UU * CC + (size_t)u0 * CC);
    float4 acc = {0.0f, 0.0f, 0.0f, 0.0f};
    #pragma unroll 4
    for (int uu = 0; uu < UCHUNK; ++uu) {
        const float  pv = sphi[uu];
        const float4 v  = tile[uu * (CC / 4) + t];
        acc.x += pv * v.x;
        acc.y += pv * v.y;
        acc.z += pv * v.z;
        acc.w += pv * v.w;
    }

    float* wptr = window + (size_t)b * CC + t * 4;
    atomicAdd(wptr + 0, acc.x);
    atomicAdd(wptr + 1, acc.y);
    atomicAdd(wptr + 2, acc.z);
    atomicAdd(wptr + 3, acc.w);
}

extern "C" void kernel_launch(void* const* d_in, const int* in_sizes, int n_in,
                              void* d_out, int out_size, void* d_ws, size_t ws_size,
                              hipStream_t stream) {
    const float* h      = (const float*)d_in[0];   // [B,H]
    const float* c_seq  = (const float*)d_in[1];   // [B,U,C]
    const float* k_prev = (const float*)d_in[2];   // [B,K]
    const float* W      = (const float*)d_in[3];   // [3K,H]
    const float* bias   = (const float*)d_in[4];   // [3K]

    float* out      = (float*)d_out;
    float* window   = out;                          // [B,C]
    float* phi      = out + BB * CC;                // [B,U]
    float* kappa_o  = out + BB * CC + BB * UU;      // [B,K]

    float* ws       = (float*)d_ws;                 // needs 3*B*K*4 = 30 KB
    float* alpha    = ws;
    float* beta     = ws + BB * KK;
    float* kappa_ws = ws + 2 * BB * KK;

    // zero the atomic accumulation target (d_ws/d_out are poisoned 0xAA)
    hipMemsetAsync(window, 0, (size_t)BB * CC * sizeof(float), stream);

    softwindow_params<<<BB, 256, 0, stream>>>(h, k_prev, W, bias,
                                              alpha, beta, kappa_ws, kappa_o);

    dim3 grid(UU / UCHUNK, BB);
    softwindow_window<<<grid, UCHUNK, 0, stream>>>(c_seq, alpha, beta, kappa_ws,
                                                   window, phi);
}

// Round 2
// 626.974 us; speedup vs baseline: 1.1687x; 1.1687x over previous
//
#include <hip/hip_runtime.h>
#include <math.h>

// Problem constants (from reference): B,H,U,C,K = 256,1024,1024,512,10
#define BB 256
#define HH 1024
#define UU 1024
#define CC 512
#define KK 10

// fp32 expf(-x) is exactly 0 (or <1e-45 subnormal) for x > ~104.
// Use 110 for margin: contributions with beta*(kappa-u)^2 > 110 are
// identically zero in the fp32 reference itself — skipping is EXACT.
#define EXP_CUTOFF 110.0f

__device__ __forceinline__ float softplus_f(float x) {
    return fmaxf(x, 0.0f) + log1pf(expf(-fabsf(x)));
}

// One block per batch row b. 256 threads = 4 waves.
// params[30] = h[b] @ W.T + bias  ->  alpha/beta/kappa + active-u bound.
__global__ void softwindow_params(const float* __restrict__ h,
                                  const float* __restrict__ k_prev,
                                  const float* __restrict__ W,
                                  const float* __restrict__ bias,
                                  float* __restrict__ alpha,
                                  float* __restrict__ beta,
                                  float* __restrict__ kappa_ws,
                                  float* __restrict__ kappa_out,
                                  int* __restrict__ u_hi) {
    __shared__ float sh[HH];
    __shared__ float sparams[3 * KK];
    __shared__ float sbound[KK];
    const int b = blockIdx.x;
    const int t = threadIdx.x;            // 0..255

    // stage h row: 1024 floats = 256 float4
    ((float4*)sh)[t] = ((const float4*)(h + (size_t)b * HH))[t];
    __syncthreads();

    const int wave = t >> 6;
    const int lane = t & 63;
    for (int j = wave; j < 3 * KK; j += 4) {
        const float* wrow = W + (size_t)j * HH;
        float sum = 0.0f;
        #pragma unroll
        for (int l = lane; l < HH; l += 64) sum += sh[l] * wrow[l];
        #pragma unroll
        for (int off = 32; off > 0; off >>= 1) sum += __shfl_down(sum, off);
        if (lane == 0) sparams[j] = sum + bias[j];
    }
    __syncthreads();

    if (t < KK) {
        float a  = softplus_f(sparams[t]) + 1e-4f;
        float be = fminf(fmaxf(softplus_f(sparams[KK + t]), 0.1f), 10.0f);
        float ka = k_prev[b * KK + t] + softplus_f(sparams[2 * KK + t]) * 0.1f;
        alpha[b * KK + t]     = a;
        beta[b * KK + t]      = be;
        kappa_ws[b * KK + t]  = ka;
        kappa_out[b * KK + t] = ka;                   // third output
        sbound[t] = ka + sqrtf(EXP_CUTOFF / be);      // u beyond this: exp == 0 in fp32
    }
    __syncthreads();
    if (t == 0) {
        float mb = sbound[0];
        #pragma unroll
        for (int k = 1; k < KK; ++k) mb = fmaxf(mb, sbound[k]);
        int hi = (mb < 0.0f) ? 0 : (int)ceilf(mb) + 1;
        u_hi[b] = hi > UU ? UU : hi;
    }
}

// One block per batch row b, 256 threads.
// Phase 1: phi[b, 0:U] (full output, exp underflow handles the tail).
// Phase 2: window[b,:] = sum_{u < u_hi[b]} phi[u] * c_seq[b,u,:]  (exact:
//          all skipped u have phi == 0 in fp32). No atomics, no memset.
__global__ void softwindow_window(const float* __restrict__ c_seq,
                                  const float* __restrict__ alpha,
                                  const float* __restrict__ beta,
                                  const float* __restrict__ kappa,
                                  const int* __restrict__ u_hi,
                                  float* __restrict__ window,
                                  float* __restrict__ phi_out) {
    __shared__ float sphi[UU];
    __shared__ float sa[KK], sb[KK], sk[KK];
    const int b = blockIdx.x;
    const int t = threadIdx.x;            // 0..255

    if (t < KK) {
        sa[t] = alpha[b * KK + t];
        sb[t] = beta[b * KK + t];
        sk[t] = kappa[b * KK + t];
    }
    __syncthreads();

    // phi for all u (4 per thread)
    #pragma unroll
    for (int i = 0; i < UU / 256; ++i) {
        const int u = t + i * 256;
        const float uf = (float)u;
        float p = 0.0f;
        #pragma unroll
        for (int k = 0; k < KK; ++k) {
            const float d = sk[k] - uf;
            p += sa[k] * __expf(-sb[k] * d * d);
        }
        sphi[u] = p;
        phi_out[(size_t)b * UU + u] = p;
    }
    __syncthreads();

    // window accumulation over the active u range only
    const int hi = u_hi[b];
    const float2* base = (const float2*)(c_seq + (size_t)b * UU * CC);
    float2 acc = {0.0f, 0.0f};
    int u = 0;
    for (; u + 4 <= hi; u += 4) {
        #pragma unroll
        for (int j = 0; j < 4; ++j) {
            const float p = sphi[u + j];
            const float2 v = base[(size_t)(u + j) * (CC / 2) + t];
            acc.x += p * v.x;
            acc.y += p * v.y;
        }
    }
    for (; u < hi; ++u) {
        const float p = sphi[u];
        const float2 v = base[(size_t)u * (CC / 2) + t];
        acc.x += p * v.x;
        acc.y += p * v.y;
    }
    ((float2*)(window + (size_t)b * CC))[t] = acc;
}

extern "C" void kernel_launch(void* const* d_in, const int* in_sizes, int n_in,
                              void* d_out, int out_size, void* d_ws, size_t ws_size,
                              hipStream_t stream) {
    const float* h      = (const float*)d_in[0];   // [B,H]
    const float* c_seq  = (const float*)d_in[1];   // [B,U,C]
    const float* k_prev = (const float*)d_in[2];   // [B,K]
    const float* W      = (const float*)d_in[3];   // [3K,H]
    const float* bias   = (const float*)d_in[4];   // [3K]

    float* out     = (float*)d_out;
    float* window  = out;                          // [B,C]
    float* phi     = out + BB * CC;                // [B,U]
    float* kappa_o = out + BB * CC + BB * UU;      // [B,K]

    float* ws       = (float*)d_ws;
    float* alpha    = ws;
    float* beta     = ws + BB * KK;
    float* kappa_ws = ws + 2 * BB * KK;
    int*   u_hi     = (int*)(ws + 3 * BB * KK);

    softwindow_params<<<BB, 256, 0, stream>>>(h, k_prev, W, bias,
                                              alpha, beta, kappa_ws, kappa_o, u_hi);

    softwindow_window<<<BB, 256, 0, stream>>>(c_seq, alpha, beta, kappa_ws,
                                              u_hi, window, phi);
}

// Round 3
// 616.908 us; speedup vs baseline: 1.1878x; 1.0163x over previous
//
#include <hip/hip_runtime.h>
#include <math.h>

// Problem constants (from reference): B,H,U,C,K = 256,1024,1024,512,10
#define BB 256
#define HH 1024
#define UU 1024
#define CC 512
#define KK 10

// fp32 expf(-x) is exactly 0 (or a <1e-45 subnormal) for x > ~104.
// Contributions with beta*(kappa-u)^2 > 110 are identically zero in the
// fp32 reference itself — skipping them is EXACT, not approximate.
#define EXP_CUTOFF 110.0f

__device__ __forceinline__ float softplus_f(float x) {
    return fmaxf(x, 0.0f) + log1pf(expf(-fabsf(x)));
}

// Fully fused: one block per batch row b, 256 threads (4 waves).
//  1. params[30] = h[b] @ W.T + bias          (LDS-staged h, shuffle-reduce)
//  2. alpha/beta/kappa + active-u bound       (t < K)
//  3. phi[b, 0:U]                             (exp underflow zeroes the tail)
//  4. window[b,:] = sum_{u<u_hi} phi*c_seq    (exact; no atomics, no ws)
__global__ void softwindow_fused(const float* __restrict__ h,
                                 const float* __restrict__ c_seq,
                                 const float* __restrict__ k_prev,
                                 const float* __restrict__ W,
                                 const float* __restrict__ bias,
                                 float* __restrict__ window,
                                 float* __restrict__ phi_out,
                                 float* __restrict__ kappa_out) {
    __shared__ float sh[HH];          // h row
    __shared__ float sphi[UU];        // phi row
    __shared__ float sparams[3 * KK];
    __shared__ float sa[KK], sb[KK], sk[KK];
    __shared__ float sbound[KK];
    __shared__ int s_hi;

    const int b = blockIdx.x;
    const int t = threadIdx.x;        // 0..255

    // ---- 1. stage h row (1024 floats = 256 float4), dot with 30 W rows ----
    ((float4*)sh)[t] = ((const float4*)(h + (size_t)b * HH))[t];
    __syncthreads();

    const int wave = t >> 6;
    const int lane = t & 63;
    for (int j = wave; j < 3 * KK; j += 4) {
        const float* wrow = W + (size_t)j * HH;
        float sum = 0.0f;
        #pragma unroll
        for (int l = lane; l < HH; l += 64) sum += sh[l] * wrow[l];
        #pragma unroll
        for (int off = 32; off > 0; off >>= 1) sum += __shfl_down(sum, off);
        if (lane == 0) sparams[j] = sum + bias[j];
    }
    __syncthreads();

    // ---- 2. activations + active-u bound ----
    if (t < KK) {
        float a  = softplus_f(sparams[t]) + 1e-4f;
        float be = fminf(fmaxf(softplus_f(sparams[KK + t]), 0.1f), 10.0f);
        float ka = k_prev[b * KK + t] + softplus_f(sparams[2 * KK + t]) * 0.1f;
        sa[t] = a;
        sb[t] = be;
        sk[t] = ka;
        kappa_out[b * KK + t] = ka;                  // third output
        sbound[t] = ka + sqrtf(EXP_CUTOFF / be);     // beyond this u: exp == 0 in fp32
    }
    __syncthreads();
    if (t == 0) {
        float mb = sbound[0];
        #pragma unroll
        for (int k = 1; k < KK; ++k) mb = fmaxf(mb, sbound[k]);
        int hi = (mb < 0.0f) ? 0 : (int)ceilf(mb) + 1;
        s_hi = hi > UU ? UU : hi;
    }
    __syncthreads();

    // ---- 3. phi for all u (4 per thread), second output ----
    #pragma unroll
    for (int i = 0; i < UU / 256; ++i) {
        const int u = t + i * 256;
        const float uf = (float)u;
        float p = 0.0f;
        #pragma unroll
        for (int k = 0; k < KK; ++k) {
            const float d = sk[k] - uf;
            p += sa[k] * __expf(-sb[k] * d * d);
        }
        sphi[u] = p;
        phi_out[(size_t)b * UU + u] = p;
    }
    __syncthreads();

    // ---- 4. window over the active u range only ----
    const int hi = s_hi;
    const float2* base = (const float2*)(c_seq + (size_t)b * UU * CC);
    float2 acc = {0.0f, 0.0f};
    int u = 0;
    for (; u + 4 <= hi; u += 4) {
        #pragma unroll
        for (int j = 0; j < 4; ++j) {
            const float p = sphi[u + j];
            const float2 v = base[(size_t)(u + j) * (CC / 2) + t];
            acc.x += p * v.x;
            acc.y += p * v.y;
        }
    }
    for (; u < hi; ++u) {
        const float p = sphi[u];
        const float2 v = base[(size_t)u * (CC / 2) + t];
        acc.x += p * v.x;
        acc.y += p * v.y;
    }
    ((float2*)(window + (size_t)b * CC))[t] = acc;
}

extern "C" void kernel_launch(void* const* d_in, const int* in_sizes, int n_in,
                              void* d_out, int out_size, void* d_ws, size_t ws_size,
                              hipStream_t stream) {
    const float* h      = (const float*)d_in[0];   // [B,H]
    const float* c_seq  = (const float*)d_in[1];   // [B,U,C]
    const float* k_prev = (const float*)d_in[2];   // [B,K]
    const float* W      = (const float*)d_in[3];   // [3K,H]
    const float* bias   = (const float*)d_in[4];   // [3K]

    float* out     = (float*)d_out;
    float* window  = out;                          // [B,C]
    float* phi     = out + BB * CC;                // [B,U]
    float* kappa_o = out + BB * CC + BB * UU;      // [B,K]

    softwindow_fused<<<BB, 256, 0, stream>>>(h, c_seq, k_prev, W, bias,
                                             window, phi, kappa_o);
}